// Round 9
// baseline (1396.307 us; speedup 1.0000x reference)
//
#include <hip/hip_runtime.h>

#define NB 4096
#define NT 512
#define NI 25
#define NH 20
#define NL 10
#define CHK 16

typedef unsigned int u32;
typedef _Float16 h2v __attribute__((ext_vector_type(2)));

__device__ __forceinline__ float rcpf(float x){
#if __has_builtin(__builtin_amdgcn_rcpf)
  return __builtin_amdgcn_rcpf(x);
#else
  return 1.0f/x;
#endif
}
__device__ __forceinline__ float exp2_fast(float x){
  float r; asm("v_exp_f32 %0, %1" : "=v"(r) : "v"(x)); return r;
}
__device__ __forceinline__ u32 pk(float a, float b){
  return __builtin_bit_cast(u32, __builtin_amdgcn_cvt_pkrtz(a, b));
}
__device__ __forceinline__ float fdot2(u32 a, u32 b, float c){
#if __has_builtin(__builtin_amdgcn_fdot2)
  return __builtin_amdgcn_fdot2(__builtin_bit_cast(h2v,a), __builtin_bit_cast(h2v,b), c, false);
#else
  h2v av = __builtin_bit_cast(h2v,a), bv = __builtin_bit_cast(h2v,b);
  return fmaf((float)av.x,(float)bv.x, fmaf((float)av.y,(float)bv.y, c));
#endif
}
__device__ __forceinline__ void anchor_u(u32 &x){ asm volatile("" : "+v"(x)); }
__device__ __forceinline__ void anchor_f(float &x){ asm volatile("" : "+v"(x)); }

// LDS: per step t%16, pair-dwords [0..13] = x[0..24]+3 zero pads (f16 pairs),
// [14..23] = h[0..19] (f16 pairs, rewritten every step), [24..25] pad.
struct Smem {
  u32   xp[CHK][26];
  float gbuf[152];   // stride 9: gate G=5k+g at k*9+g  (stride 9 coprime 32 -> no 4-way bank alias)
  float zbuf[12];
};

// Combined operand positions: s in [0,48): s<25 -> x[s]; s<28 -> 0; else h[s-28].
// Lane (p,k): owns gates G=5k..5k+4, positions 12p..12p+11 (6 f16 pairs).
__device__ __forceinline__ void load_w(
    const float* __restrict__ Wih, const float* __restrict__ Whh,
    const float* __restrict__ bih, const float* __restrict__ bhh,
    int p, int k, float SC, u32 (&w2)[5][6], float (&bias)[5])
{
#pragma unroll
  for (int g=0; g<5; ++g){
    const int G = 5*k+g;
    const float* wi = Wih + G*25;
    const float* wh = Whh + G*20;
#pragma unroll
    for (int j=0; j<6; ++j){
      const int s0 = 12*p + 2*j, s1 = s0+1;
      float a = (s0<25) ? wi[s0] : ((s0<28) ? 0.f : wh[s0-28]);
      float b = (s1<25) ? wi[s1] : ((s1<28) ? 0.f : wh[s1-28]);
      w2[g][j] = pk(a*SC, b*SC);
      anchor_u(w2[g][j]);
    }
    bias[g] = (p==0) ? SC*(bih[G]+bhh[G]) : 0.f;
    anchor_f(bias[g]);
  }
}

template<bool DEC>
__device__ __forceinline__ void lstm_loop(
    const float* __restrict__ xrow, Smem* sm, int lane, int p, int k,
    const u32 (&w2)[5][6], const float (&bias)[5], float& c,
    const u32 (&ow2)[10], float obias, float* __restrict__ xhat)
{
  const bool is_g = ((k>>2)==2);
  const int lin = lane;
  const int ai  = (lin/5)*9 + (lin%5);      // i-gate addr for unit lin (stride 9)
  const float TC2 = -2.8853900817779268f;   // -2*log2(e)

  for (int t=0; t<NT; ++t){
    const int tc = t & (CHK-1);
    if (tc == 0){
      __syncthreads();                       // old chunk fully consumed
      const float* gsrc = xrow + (size_t)t*NI;
#pragma unroll
      for (int it=0; it<4; ++it){
        int P = lane + it*64;                // 224 pairs = 16 steps x 14
        if (P < 14*CHK){
          int tt = P/14, pr = P - tt*14;
          int i0 = 2*pr, i1 = i0+1;
          float a = (i0<NI) ? gsrc[tt*NI+i0] : 0.f;
          float b = (i1<NI) ? gsrc[tt*NI+i1] : 0.f;
          sm->xp[tt][pr] = pk(a,b);
        }
      }
    }
    __syncthreads();                         // orders h-write(t-1) + staging -> reads

    if (DEC && t>0 && lin<NI){
      // project h after step t-1 (h pairs of row tc were written at end of t-1)
      const u32* hp = &sm->xp[tc][14];
      float a = obias;
#pragma unroll
      for (int j=0;j<10;++j) a = fdot2(ow2[j], hp[j], a);
      xhat[(size_t)(t-1)*NI + lin] = a;
    }

    // uniform operand slice: 6 pair-dwords at xp[tc][6p .. 6p+5]
    const u32* opb = &sm->xp[tc][6*p];
    u32 op[6];
    *(uint2*)&op[0] = *(const uint2*)(opb+0);
    *(uint2*)&op[2] = *(const uint2*)(opb+2);
    *(uint2*)&op[4] = *(const uint2*)(opb+4);

    float acc[5];
#pragma unroll
    for (int g=0; g<5; ++g){
      float a = bias[g];
#pragma unroll
      for (int j=0; j<6; ++j) a = fdot2(w2[g][j], op[j], a);
      acc[g] = a;
    }
#pragma unroll
    for (int g=0; g<5; ++g){
      acc[g] += __shfl_xor(acc[g], 16);
      acc[g] += __shfl_xor(acc[g], 32);
    }

    // distributed activation: every lane activates gate 5k+p (acc[p]);
    // p==0 lanes additionally handle gate 5k+4. All p hold full sums.
    {
      float a = acc[0];
      if (p==1) a = acc[1];
      if (p==2) a = acc[2];
      if (p==3) a = acc[3];
      float e = exp2_fast(a);                // SC-folded: = exp(-pre) / exp(-2*pre)
      float s = rcpf(1.f + e);
      sm->gbuf[k*9+p] = is_g ? (2.f*s - 1.f) : s;
      if (p==0){
        float e4 = exp2_fast(acc[4]);
        float s4 = rcpf(1.f + e4);
        sm->gbuf[k*9+4] = is_g ? (2.f*s4 - 1.f) : s4;
      }
    }
    __syncthreads();
    if (lin < NH){
      float ig = sm->gbuf[ai];
      float fg = sm->gbuf[ai+36];
      float gg = sm->gbuf[ai+72];
      float og = sm->gbuf[ai+108];
      float cn = fmaf(fg, c, ig*gg);
      c = cn;
      float e  = exp2_fast(cn*TC2);
      float th = 2.f*rcpf(1.f + e) - 1.f;
      float h  = og*th;
      // h pairs for the NEXT step's row
      ((_Float16*)&sm->xp[(t+1)&(CHK-1)][14])[lin] = (_Float16)h;
    }
  }
}

__global__ __launch_bounds__(64)
__attribute__((amdgpu_waves_per_eu(4,4)))
void lstm_vae_kernel(
  const float* __restrict__ x, const float* __restrict__ h0, const float* __restrict__ c0,
  const float* __restrict__ noise,
  const float* __restrict__ eWih, const float* __restrict__ eWhh, const float* __restrict__ ebih, const float* __restrict__ ebhh,
  const float* __restrict__ dWih, const float* __restrict__ dWhh, const float* __restrict__ dbih, const float* __restrict__ dbhh,
  const float* __restrict__ mW, const float* __restrict__ mb,
  const float* __restrict__ lW, const float* __restrict__ lb,
  const float* __restrict__ iW, const float* __restrict__ ib,
  const float* __restrict__ oW, const float* __restrict__ ob,
  float* __restrict__ out)
{
  __shared__ Smem sm;
  const int lane = threadIdx.x;
  const int p = lane>>4, k = lane&15, lin = lane;
  const int b = blockIdx.x;
  const float* xrow = x + (size_t)b*NT*NI;
  const bool is_g = ((k>>2)==2);
  const float L2E = 1.4426950408889634f;
  const float SC  = is_g ? (-2.f*L2E) : (-L2E);

  u32 w2[5][6]; float bias[5];
  u32 ow2[10] = {0,0,0,0,0,0,0,0,0,0};
  float obias = 0.f, c = 0.f;

  if (lin < NH){
    ((_Float16*)&sm.xp[0][14])[lin] = (_Float16)h0[(size_t)b*NH + lin];
    c = c0[(size_t)b*NH + lin];
  }
  load_w(eWih, eWhh, ebih, ebhh, p, k, SC, w2, bias);
  __syncthreads();

  lstm_loop<false>(xrow, &sm, lane, p, k, w2, bias, c, ow2, obias, nullptr);
  __syncthreads();   // final enc h pairs are in xp[0][14..23] (written at t=NT-1)

  const size_t OFF1 = (size_t)NB*NT*NI;
  const size_t OFF2 = OFF1 + (size_t)NB*NL;
  const size_t OFF3 = OFF2 + (size_t)NB*NL;
  const size_t OFF4 = OFF3 + (size_t)NB*NL;
  const size_t OFF5 = OFF4 + (size_t)NB*NH;

  if (lin < NH){
    out[OFF4 + (size_t)b*NH + lin] = (float)((_Float16*)&sm.xp[0][14])[lin];
    out[OFF5 + (size_t)b*NH + lin] = c;
  }
  if (lin < NL){
    float h[20];
#pragma unroll
    for (int j=0;j<10;++j){
      h2v hh = __builtin_bit_cast(h2v, sm.xp[0][14+j]);
      h[2*j] = (float)hh.x; h[2*j+1] = (float)hh.y;
    }
    float mm = mb[lin], lv = lb[lin];
#pragma unroll
    for (int j=0;j<20;++j){
      mm = fmaf(mW[lin*20+j], h[j], mm);
      lv = fmaf(lW[lin*20+j], h[j], lv);
    }
    float sd = __expf(0.5f*lv);
    float zz = fmaf(noise[(size_t)b*NL + lin], sd, mm);
    out[OFF1 + (size_t)b*NL + lin] = mm;
    out[OFF2 + (size_t)b*NL + lin] = lv;
    out[OFF3 + (size_t)b*NL + lin] = zz;
    sm.zbuf[lin] = zz;
  }
  __syncthreads();
  if (lin < NH){
    float hd = ib[lin];
#pragma unroll
    for (int l=0;l<NL;++l) hd = fmaf(iW[lin*NL+l], sm.zbuf[l], hd);
    c = hd;
    ((_Float16*)&sm.xp[0][14])[lin] = (_Float16)hd;   // decoder h for t=0
  }
  load_w(dWih, dWhh, dbih, dbhh, p, k, SC, w2, bias);
  if (lin < NI){
#pragma unroll
    for (int j=0;j<10;++j) ow2[j] = pk(oW[lin*20+2*j], oW[lin*20+2*j+1]);
    obias = ob[lin];
  }
#pragma unroll
  for (int j=0;j<10;++j) anchor_u(ow2[j]);
  __syncthreads();

  float* xhat = out + (size_t)b*NT*NI;
  lstm_loop<true>(xrow, &sm, lane, p, k, w2, bias, c, ow2, obias, xhat);
  __syncthreads();   // final dec h pairs in xp[0][14..23]

  if (lin < NI){
    const u32* hp = &sm.xp[0][14];
    float a = obias;
#pragma unroll
    for (int j=0;j<10;++j) a = fdot2(ow2[j], hp[j], a);
    xhat[(size_t)(NT-1)*NI + lin] = a;
  }
}

extern "C" void kernel_launch(void* const* d_in, const int* in_sizes, int n_in,
                              void* d_out, int out_size, void* d_ws, size_t ws_size,
                              hipStream_t stream) {
  const float* x     = (const float*)d_in[0];
  const float* h0    = (const float*)d_in[1];
  const float* c0    = (const float*)d_in[2];
  const float* noise = (const float*)d_in[3];
  const float* eWih  = (const float*)d_in[4];
  const float* eWhh  = (const float*)d_in[5];
  const float* ebih  = (const float*)d_in[6];
  const float* ebhh  = (const float*)d_in[7];
  const float* dWih  = (const float*)d_in[8];
  const float* dWhh  = (const float*)d_in[9];
  const float* dbih  = (const float*)d_in[10];
  const float* dbhh  = (const float*)d_in[11];
  const float* mW    = (const float*)d_in[12];
  const float* mb    = (const float*)d_in[13];
  const float* lW    = (const float*)d_in[14];
  const float* lb    = (const float*)d_in[15];
  const float* iW    = (const float*)d_in[16];
  const float* ib    = (const float*)d_in[17];
  const float* oW    = (const float*)d_in[18];
  const float* ob    = (const float*)d_in[19];
  float* out = (float*)d_out;

  hipLaunchKernelGGL(lstm_vae_kernel, dim3(NB), dim3(64), 0, stream,
                     x, h0, c0, noise,
                     eWih, eWhh, ebih, ebhh,
                     dWih, dWhh, dbih, dbhh,
                     mW, mb, lW, lb, iW, ib, oW, ob, out);
}